// Round 18
// baseline (255.901 us; speedup 1.0000x reference)
//
#include <hip/hip_runtime.h>
#include <hip/hip_fp16.h>

#define N_NODES 50000
#define N_EDGES 800000
#define E_TOT   850000           // edges + self loops
#define IN_DIM  128
#define HID     64
#define HEADS   4
#define C1      256              // HEADS*HID
#define OUT_DIM 64
#define NEG_SLOPE 0.2f

#define CP_NODES   32                              // nodes per proj block
#define CP_BLOCKS  ((N_NODES + CP_NODES - 1) / CP_NODES)   // 1563
#define COUNT_BLOCKS ((E_TOT + 255) / 256)         // 3321
#define NB_SCAN ((N_NODES + 255) / 256)            // 196

typedef __attribute__((ext_vector_type(8))) short v8s;   // 8 bf16 (4 VGPRs)
typedef __attribute__((ext_vector_type(4))) float v4f;   // MFMA accumulator

// ---- bf16 helpers (manual: bf16 = top 16 bits of fp32, RNE) ----------------
__device__ __forceinline__ unsigned int bf16_rne(float f) {
    unsigned int u = __float_as_uint(f);
    return (u + 0x7FFFu + ((u >> 16) & 1u)) >> 16;
}
__device__ __forceinline__ unsigned int bf16_pack2(float a, float b) {
    return bf16_rne(a) | (bf16_rne(b) << 16);
}
__device__ __forceinline__ float bf16_lo(unsigned int u) { return __uint_as_float(u << 16); }
__device__ __forceinline__ float bf16_hi(unsigned int u) { return __uint_as_float(u & 0xFFFF0000u); }

// ---- fp16 pack helpers for edge weights ------------------------------------
__device__ __forceinline__ unsigned int f16_pack2(float a, float b) {
    __half2 h = __floats2half2_rn(a, b);
    return *(unsigned int*)&h;
}
__device__ __forceinline__ float2 f16_unp2(unsigned int u) {
    __half2 h = *(__half2*)&u;
    return __half22float2(h);
}

// ---------------------------------------------------------------------------
// prep: p_src/p_dst collapse the layer-1 logit projection; v_s/v_d/v_z
// collapse ALL consumers of h2; cst = b2.fc_w + fc_b; W1 -> bf16 B-fragments.
// ---------------------------------------------------------------------------
__global__ __launch_bounds__(512) void prep_kernel(
    const float* __restrict__ W1, const float* __restrict__ a_src1,
    const float* __restrict__ a_dst1,
    const float* __restrict__ W2, const float* __restrict__ a_src2,
    const float* __restrict__ a_dst2, const float* __restrict__ b2,
    const float* __restrict__ fc_w, const float* __restrict__ fc_b,
    float* __restrict__ p_src, float* __restrict__ p_dst,
    float* __restrict__ v_s, float* __restrict__ v_d, float* __restrict__ v_z,
    float* __restrict__ cst, unsigned int* __restrict__ W1b)
{
    const int t = threadIdx.x;                 // 512 = 128 k * 4 h
    const int k = t >> 2, h = t & 3;
    const float* wrow = W1 + k * C1 + h * HID;
    const float* as = a_src1 + h * HID;
    const float* ad = a_dst1 + h * HID;
    float s = 0.f, d = 0.f;
    for (int c = 0; c < HID; c++) {
        float w = wrow[c];
        s = fmaf(w, as[c], s);
        d = fmaf(w, ad[c], d);
    }
    p_src[k * HEADS + h] = s;
    p_dst[k * HEADS + h] = d;

    if (t < C1) {                              // layer-2 collapse vectors
        const float* w2row = W2 + t * OUT_DIM;
        float vs = 0.f, vd = 0.f, vz = 0.f;
        for (int c = 0; c < OUT_DIM; c++) {
            float w = w2row[c];
            vs = fmaf(w, a_src2[c], vs);
            vd = fmaf(w, a_dst2[c], vd);
            vz = fmaf(w, fc_w[c], vz);
        }
        v_s[t] = vs; v_d[t] = vd; v_z[t] = vz;
    }
    if (t == 0) {
        float s2 = 0.f;
        for (int c = 0; c < OUT_DIM; c++) s2 = fmaf(b2[c], fc_w[c], s2);
        cst[0] = s2 + fc_b[0];
    }

    // W1 -> bf16 B-fragment packing (16384 uints = 64 KB)
    for (int idx = t; idx < 16384; idx += 512) {
        int i    = idx & 3;
        int lane = (idx >> 2) & 63;
        int kk   = (idx >> 8) & 3;
        int nt   = (idx >> 10) & 3;
        int hh   = idx >> 12;
        int k0 = kk * 32 + (lane >> 4) * 8 + i * 2;
        int c  = hh * 64 + nt * 16 + (lane & 15);
        W1b[idx] = bf16_pack2(W1[(size_t)k0 * C1 + c], W1[(size_t)(k0 + 1) * C1 + c]);
    }
}

// ---------------------------------------------------------------------------
// convproj_count: fused launch.
//  Blocks [0, CP_BLOCKS): 32 nodes/block. Wave = 8 nodes; lane = (node-sub,
//    16-ch chunk) -> width-8 shuffle reduce (3 rounds, was 6 width-64 ones).
//  Blocks [CP_BLOCKS, +COUNT_BLOCKS): degree count; stores posE[j].
// ---------------------------------------------------------------------------
__global__ __launch_bounds__(256) void convproj_count_kernel(
    const float* __restrict__ x, const float* __restrict__ p_src,
    const float* __restrict__ p_dst, const int* __restrict__ dst_a,
    float* __restrict__ as1, float* __restrict__ ad1,
    unsigned int* __restrict__ xb, int* __restrict__ deg,
    int* __restrict__ posE)
{
    if (blockIdx.x >= CP_BLOCKS) {             // ---- count part ----
        int j = (blockIdx.x - CP_BLOCKS) * 256 + threadIdx.x;
        if (j < E_TOT) {
            int d = (j < N_EDGES) ? dst_a[j] : (j - N_EDGES);   // self loop
            posE[j] = atomicAdd(&deg[d], 1);
        }
        return;
    }
    // ---- proj + convert part ----
    __shared__ float ps[IN_DIM * HEADS];       // 2 KB
    __shared__ float pd[IN_DIM * HEADS];       // 2 KB
    const int t = threadIdx.x;
    for (int i = t; i < IN_DIM * HEADS; i += 256) { ps[i] = p_src[i]; pd[i] = p_dst[i]; }
    __syncthreads();
    const int wv   = t >> 6;
    const int lane = t & 63;
    const int sub  = lane >> 3;                // node sub-index 0..7
    const int ck   = lane & 7;                 // 16-channel chunk 0..7
    const int node = blockIdx.x * CP_NODES + wv * 8 + sub;
    if (node >= N_NODES) return;
    const float* xr = x + (size_t)node * IN_DIM + ck * 16;
    float s0 = 0.f, s1 = 0.f, s2 = 0.f, s3 = 0.f;
    float d0 = 0.f, d1 = 0.f, d2 = 0.f, d3 = 0.f;
    unsigned int* xo = xb + (size_t)node * 64 + ck * 8;
    #pragma unroll
    for (int q = 0; q < 4; q++) {              // 4 x float4 = 16 channels
        float4 xv = *(const float4*)(xr + q * 4);
        xo[q * 2 + 0] = bf16_pack2(xv.x, xv.y);
        xo[q * 2 + 1] = bf16_pack2(xv.z, xv.w);
        const int c0 = (ck * 16 + q * 4) * HEADS;
        float4 pa = *(const float4*)(ps + c0);
        float4 pb = *(const float4*)(ps + c0 + 4);
        float4 pc = *(const float4*)(ps + c0 + 8);
        float4 pdv = *(const float4*)(ps + c0 + 12);
        s0 = fmaf(xv.x, pa.x, s0); s1 = fmaf(xv.x, pa.y, s1);
        s2 = fmaf(xv.x, pa.z, s2); s3 = fmaf(xv.x, pa.w, s3);
        s0 = fmaf(xv.y, pb.x, s0); s1 = fmaf(xv.y, pb.y, s1);
        s2 = fmaf(xv.y, pb.z, s2); s3 = fmaf(xv.y, pb.w, s3);
        s0 = fmaf(xv.z, pc.x, s0); s1 = fmaf(xv.z, pc.y, s1);
        s2 = fmaf(xv.z, pc.z, s2); s3 = fmaf(xv.z, pc.w, s3);
        s0 = fmaf(xv.w, pdv.x, s0); s1 = fmaf(xv.w, pdv.y, s1);
        s2 = fmaf(xv.w, pdv.z, s2); s3 = fmaf(xv.w, pdv.w, s3);
        float4 qa = *(const float4*)(pd + c0);
        float4 qb = *(const float4*)(pd + c0 + 4);
        float4 qc = *(const float4*)(pd + c0 + 8);
        float4 qd = *(const float4*)(pd + c0 + 12);
        d0 = fmaf(xv.x, qa.x, d0); d1 = fmaf(xv.x, qa.y, d1);
        d2 = fmaf(xv.x, qa.z, d2); d3 = fmaf(xv.x, qa.w, d3);
        d0 = fmaf(xv.y, qb.x, d0); d1 = fmaf(xv.y, qb.y, d1);
        d2 = fmaf(xv.y, qb.z, d2); d3 = fmaf(xv.y, qb.w, d3);
        d0 = fmaf(xv.z, qc.x, d0); d1 = fmaf(xv.z, qc.y, d1);
        d2 = fmaf(xv.z, qc.z, d2); d3 = fmaf(xv.z, qc.w, d3);
        d0 = fmaf(xv.w, qd.x, d0); d1 = fmaf(xv.w, qd.y, d1);
        d2 = fmaf(xv.w, qd.z, d2); d3 = fmaf(xv.w, qd.w, d3);
    }
    #pragma unroll
    for (int off = 4; off; off >>= 1) {        // width-8 reduce over chunks
        s0 += __shfl_down(s0, off, 8); s1 += __shfl_down(s1, off, 8);
        s2 += __shfl_down(s2, off, 8); s3 += __shfl_down(s3, off, 8);
        d0 += __shfl_down(d0, off, 8); d1 += __shfl_down(d1, off, 8);
        d2 += __shfl_down(d2, off, 8); d3 += __shfl_down(d3, off, 8);
    }
    if (ck == 0) {
        float4 sv = {s0, s1, s2, s3};
        float4 dv = {d0, d1, d2, d3};
        *(float4*)(as1 + node * 4) = sv;
        *(float4*)(ad1 + node * 4) = dv;
    }
}

// ---------------------------------------------------------------------------
// Parallel CSR scan: blocksum -> scanbsum -> expand
// ---------------------------------------------------------------------------
__global__ __launch_bounds__(256) void blocksum_kernel(
    const int* __restrict__ deg, int* __restrict__ bsum)
{
    __shared__ int ps[256];
    const int t = threadIdx.x;
    int i = blockIdx.x * 256 + t;
    ps[t] = (i < N_NODES) ? deg[i] : 0;
    __syncthreads();
    for (int off = 128; off; off >>= 1) {
        if (t < off) ps[t] += ps[t + off];
        __syncthreads();
    }
    if (t == 0) bsum[blockIdx.x] = ps[0];
}

__global__ __launch_bounds__(256) void scanbsum_kernel(
    const int* __restrict__ bsum, int* __restrict__ boff)
{
    __shared__ int ps[256];
    const int t = threadIdx.x;
    ps[t] = (t < NB_SCAN) ? bsum[t] : 0;
    __syncthreads();
    for (int off = 1; off < 256; off <<= 1) {
        int u = (t >= off) ? ps[t - off] : 0;
        __syncthreads();
        ps[t] += u;
        __syncthreads();
    }
    boff[t] = (t > 0) ? ps[t - 1] : 0;         // exclusive
}

__global__ __launch_bounds__(256) void expand_kernel(
    const int* __restrict__ deg, const int* __restrict__ boff,
    int* __restrict__ rowptr)
{
    __shared__ int ps[256];
    const int t = threadIdx.x;
    int i = blockIdx.x * 256 + t;
    int v = (i < N_NODES) ? deg[i] : 0;
    ps[t] = v;
    __syncthreads();
    for (int off = 1; off < 256; off <<= 1) {
        int u = (t >= off) ? ps[t - off] : 0;
        __syncthreads();
        ps[t] += u;
        __syncthreads();
    }
    if (i <= N_NODES) rowptr[i] = boff[blockIdx.x] + ps[t] - v;   // exclusive
}

// ---------------------------------------------------------------------------
// fillw3: atomic-free CSR fill with ONE 16 B sorted record per edge:
// rec[slot] = {src, w01(2xf16), w23(2xf16), 0}.
// ---------------------------------------------------------------------------
__global__ void fillw3_kernel(const int* __restrict__ src_a, const int* __restrict__ dst_a,
                              const int* __restrict__ rowptr, const int* __restrict__ posE,
                              const float* __restrict__ as1, const float* __restrict__ ad1,
                              int4* __restrict__ rec)
{
    int j = blockIdx.x * blockDim.x + threadIdx.x;
    if (j >= E_TOT) return;
    int s, d;
    if (j < N_EDGES) { s = src_a[j]; d = dst_a[j]; }
    else             { s = j - N_EDGES; d = s; }
    int slot = rowptr[d] + posE[j];
    float4 A  = *(const float4*)(as1 + s * 4);
    float4 Dv = *(const float4*)(ad1 + d * 4);
    float a0 = A.x + Dv.x, a1 = A.y + Dv.y, a2 = A.z + Dv.z, a3 = A.w + Dv.w;
    a0 = a0 > 0.f ? a0 : NEG_SLOPE * a0;
    a1 = a1 > 0.f ? a1 : NEG_SLOPE * a1;
    a2 = a2 > 0.f ? a2 : NEG_SLOPE * a2;
    a3 = a3 > 0.f ? a3 : NEG_SLOPE * a3;
    int4 r;
    r.x = s;
    r.y = (int)f16_pack2(__expf(a0), __expf(a1));
    r.z = (int)f16_pack2(__expf(a2), __expf(a3));
    r.w = 0;
    rec[slot] = r;                             // single 16 B scatter
}

// ---------------------------------------------------------------------------
// agg1x: xaggb[n][h][k] (bf16) = softmax-weighted sum of xb[src] rows (bf16).
// One wave per dst node; unroll x8 -> 8 xb-row gathers in flight, 8 records
// = two 64 B lines.
// ---------------------------------------------------------------------------
__global__ __launch_bounds__(256) void agg1x_kernel(
    const int* __restrict__ rowptr, const int4* __restrict__ rec,
    const unsigned int* __restrict__ xb, unsigned int* __restrict__ xaggb)
{
    int gid  = blockIdx.x * blockDim.x + threadIdx.x;
    int n    = gid >> 6;
    int lane = threadIdx.x & 63;
    if (n >= N_NODES) return;
    const int e0 = rowptr[n], e1 = rowptr[n + 1];

    float2 acc0 = {0,0}, acc1 = {0,0}, acc2 = {0,0}, acc3 = {0,0};
    float den0 = 0, den1 = 0, den2 = 0, den3 = 0;
    int e = e0;
    for (; e + 8 <= e1; e += 8) {              // 8 gathers in flight
        int4 r[8];
        unsigned int xu[8];
        #pragma unroll
        for (int i = 0; i < 8; i++) r[i] = rec[e + i];
        #pragma unroll
        for (int i = 0; i < 8; i++) xu[i] = xb[(size_t)r[i].x * 64 + lane];
        #pragma unroll
        for (int i = 0; i < 8; i++) {
            float2 Wa = f16_unp2(r[i].y), Wb = f16_unp2(r[i].z);
            float xa = bf16_lo(xu[i]), xbv = bf16_hi(xu[i]);
            acc0.x = fmaf(Wa.x, xa, acc0.x); acc0.y = fmaf(Wa.x, xbv, acc0.y);
            acc1.x = fmaf(Wa.y, xa, acc1.x); acc1.y = fmaf(Wa.y, xbv, acc1.y);
            acc2.x = fmaf(Wb.x, xa, acc2.x); acc2.y = fmaf(Wb.x, xbv, acc2.y);
            acc3.x = fmaf(Wb.y, xa, acc3.x); acc3.y = fmaf(Wb.y, xbv, acc3.y);
            den0 += Wa.x; den1 += Wa.y; den2 += Wb.x; den3 += Wb.y;
        }
    }
    for (; e + 4 <= e1; e += 4) {              // 4-tail
        int4 r[4];
        unsigned int xu[4];
        #pragma unroll
        for (int i = 0; i < 4; i++) r[i] = rec[e + i];
        #pragma unroll
        for (int i = 0; i < 4; i++) xu[i] = xb[(size_t)r[i].x * 64 + lane];
        #pragma unroll
        for (int i = 0; i < 4; i++) {
            float2 Wa = f16_unp2(r[i].y), Wb = f16_unp2(r[i].z);
            float xa = bf16_lo(xu[i]), xbv = bf16_hi(xu[i]);
            acc0.x = fmaf(Wa.x, xa, acc0.x); acc0.y = fmaf(Wa.x, xbv, acc0.y);
            acc1.x = fmaf(Wa.y, xa, acc1.x); acc1.y = fmaf(Wa.y, xbv, acc1.y);
            acc2.x = fmaf(Wb.x, xa, acc2.x); acc2.y = fmaf(Wb.x, xbv, acc2.y);
            acc3.x = fmaf(Wb.y, xa, acc3.x); acc3.y = fmaf(Wb.y, xbv, acc3.y);
            den0 += Wa.x; den1 += Wa.y; den2 += Wb.x; den3 += Wb.y;
        }
    }
    for (; e < e1; e++) {
        int4 r0 = rec[e];
        unsigned int xu = xb[(size_t)r0.x * 64 + lane];
        float2 Wa = f16_unp2(r0.y), Wb = f16_unp2(r0.z);
        float xa = bf16_lo(xu), xbv = bf16_hi(xu);
        acc0.x = fmaf(Wa.x, xa, acc0.x); acc0.y = fmaf(Wa.x, xbv, acc0.y);
        acc1.x = fmaf(Wa.y, xa, acc1.x); acc1.y = fmaf(Wa.y, xbv, acc1.y);
        acc2.x = fmaf(Wb.x, xa, acc2.x); acc2.y = fmaf(Wb.x, xbv, acc2.y);
        acc3.x = fmaf(Wb.y, xa, acc3.x); acc3.y = fmaf(Wb.y, xbv, acc3.y);
        den0 += Wa.x; den1 += Wa.y; den2 += Wb.x; den3 += Wb.y;
    }
    float i0 = 1.f / (den0 + 1e-16f), i1 = 1.f / (den1 + 1e-16f);
    float i2 = 1.f / (den2 + 1e-16f), i3 = 1.f / (den3 + 1e-16f);
    unsigned int* o = xaggb + (size_t)n * 256 + lane;      // row = 256 uints
    o[0 * 64] = bf16_pack2(acc0.x * i0, acc0.y * i0);
    o[1 * 64] = bf16_pack2(acc1.x * i1, acc1.y * i1);
    o[2 * 64] = bf16_pack2(acc2.x * i2, acc2.y * i2);
    o[3 * 64] = bf16_pack2(acc3.x * i3, acc3.y * i3);
}

// ---------------------------------------------------------------------------
// mlp7: MFMA phase B. 16 nodes/block, wave = head. (unchanged)
// ---------------------------------------------------------------------------
__global__ __launch_bounds__(256, 4) void mlp7_kernel(
    const unsigned int* __restrict__ xaggb,
    const unsigned int* __restrict__ W1b, const float* __restrict__ b1,
    const float* __restrict__ v_s, const float* __restrict__ v_d,
    const float* __restrict__ v_z,
    float2* __restrict__ az, float* __restrict__ ad2)
{
    __shared__ unsigned int xsh[16 * 260];     // 16.6 KB bf16 tile (+pad)
    __shared__ float pr[4 * 16 * 3];           // 768 B cross-wave partials
    const int t = threadIdx.x;
    const int nodeBase = blockIdx.x * 16;
    const int h = t >> 6;                      // wave = head
    const int lane = t & 63;

    {   // ---- Phase A: stage 16x512ch bf16 tile (no conversion) ----
        const unsigned int* gsrc = xaggb + (size_t)nodeBase * 256;
        #pragma unroll
        for (int i = 0; i < 4; i++) {
            int iu = i * 1024 + t * 4;         // uint index in 4096-uint tile
            uint4 v = *(const uint4*)(gsrc + iu);
            int n = iu >> 8, c = iu & 255;
            *(uint4*)(xsh + n * 260 + c) = v;
        }
    }
    __syncthreads();

    {   // ---- Phase B: MFMA + register epilogue ----
        const int m = lane & 15, quad = lane >> 4;
        const unsigned int* abase = xsh + m * 260 + h * 64 + quad * 4;
        v8s af0 = *(const v8s*)(abase + 0);
        v8s af1 = *(const v8s*)(abase + 16);
        v8s af2 = *(const v8s*)(abase + 32);
        v8s af3 = *(const v8s*)(abase + 48);

        float Sr[4] = {0,0,0,0}, Dr[4] = {0,0,0,0}, Zr[4] = {0,0,0,0};
        #pragma unroll
        for (int nt = 0; nt < 4; nt++) {
            const unsigned int* bbase = W1b + (size_t)(h * 16 + nt * 4) * 256 + lane * 4;
            v4f acc = {0.f, 0.f, 0.f, 0.f};
            acc = __builtin_amdgcn_mfma_f32_16x16x32_bf16(af0, *(const v8s*)(bbase + 0 * 256), acc, 0, 0, 0);
            acc = __builtin_amdgcn_mfma_f32_16x16x32_bf16(af1, *(const v8s*)(bbase + 1 * 256), acc, 0, 0, 0);
            acc = __builtin_amdgcn_mfma_f32_16x16x32_bf16(af2, *(const v8s*)(bbase + 2 * 256), acc, 0, 0, 0);
            acc = __builtin_amdgcn_mfma_f32_16x16x32_bf16(af3, *(const v8s*)(bbase + 3 * 256), acc, 0, 0, 0);
            const int c = h * 64 + nt * 16 + m;
            float bb = b1[c], vsc = v_s[c], vdc = v_d[c], vzc = v_z[c];
            #pragma unroll
            for (int r = 0; r < 4; r++) {
                float o = acc[r] + bb;
                o = o > 0.f ? o : __expf(o) - 1.f;     // ELU
                Sr[r] = fmaf(o, vsc, Sr[r]);
                Dr[r] = fmaf(o, vdc, Dr[r]);
                Zr[r] = fmaf(o, vzc, Zr[r]);
            }
        }
        #pragma unroll
        for (int off = 8; off; off >>= 1) {            // reduce over 16 cols
            #pragma unroll
            for (int r = 0; r < 4; r++) {
                Sr[r] += __shfl_down(Sr[r], off, 16);
                Dr[r] += __shfl_down(Dr[r], off, 16);
                Zr[r] += __shfl_down(Zr[r], off, 16);
            }
        }
        if (m == 0) {
            #pragma unroll
            for (int r = 0; r < 4; r++) {
                const int row = quad * 4 + r;          // local node 0..15
                pr[(h * 16 + row) * 3 + 0] = Sr[r];
                pr[(h * 16 + row) * 3 + 1] = Dr[r];
                pr[(h * 16 + row) * 3 + 2] = Zr[r];
            }
        }
    }
    __syncthreads();

    if (t < 16) {   // ---- cross-head reduce + store ----
        float s = 0.f, d = 0.f, z = 0.f;
        #pragma unroll
        for (int w = 0; w < 4; w++) {
            s += pr[(w * 16 + t) * 3 + 0];
            d += pr[(w * 16 + t) * 3 + 1];
            z += pr[(w * 16 + t) * 3 + 2];
        }
        const int node = nodeBase + t;
        float2 azv = {s, z};
        az[node]  = azv;
        ad2[node] = d;
    }
}

// ---------------------------------------------------------------------------
// agg2z: out[n] = sum_e w_e * z[src] / sum_e w_e + cst.  Reads rec[e].x.
// ---------------------------------------------------------------------------
__global__ __launch_bounds__(256) void agg2z_kernel(
    const int* __restrict__ rowptr, const int4* __restrict__ rec,
    const float2* __restrict__ az, const float* __restrict__ ad2,
    const float* __restrict__ cst, float* __restrict__ out)
{
    int gid  = blockIdx.x * blockDim.x + threadIdx.x;
    int n    = gid >> 3;                       // 8 lanes per node
    int sl   = threadIdx.x & 7;
    if (n >= N_NODES) return;
    const float adh = ad2[n];
    const int e0 = rowptr[n], e1 = rowptr[n + 1];

    float acc = 0.f, den = 0.f;
    for (int e = e0 + sl; e < e1; e += 8) {
        int s = rec[e].x;
        float2 v = az[s];
        float a = v.x + adh;
        a = a > 0.f ? a : NEG_SLOPE * a;
        float w = __expf(a);
        acc = fmaf(w, v.y, acc);
        den += w;
    }
    #pragma unroll
    for (int off = 4; off; off >>= 1) {
        acc += __shfl_down(acc, off, 8);
        den += __shfl_down(den, off, 8);
    }
    if (sl == 0) out[n] = acc / (den + 1e-16f) + cst[0];
}

extern "C" void kernel_launch(void* const* d_in, const int* in_sizes, int n_in,
                              void* d_out, int out_size, void* d_ws, size_t ws_size,
                              hipStream_t stream)
{
    const float* x      = (const float*)d_in[0];
    const int*   ei     = (const int*)d_in[1];
    const float* W1     = (const float*)d_in[2];
    const float* a_src1 = (const float*)d_in[3];
    const float* a_dst1 = (const float*)d_in[4];
    const float* b1     = (const float*)d_in[5];
    const float* W2     = (const float*)d_in[6];
    const float* a_src2 = (const float*)d_in[7];
    const float* a_dst2 = (const float*)d_in[8];
    const float* b2     = (const float*)d_in[9];
    const float* fc_w   = (const float*)d_in[10];
    const float* fc_b   = (const float*)d_in[11];
    float* out = (float*)d_out;

    const int* srcA = ei;
    const int* dstA = ei + N_EDGES;

    // workspace layout (pads after index buffers as OOB insurance)
    float* ws = (float*)d_ws;
    size_t off = 0;
    unsigned int* xaggb = (unsigned int*)(ws + off); off += (size_t)N_NODES * 256;  // 51.2 MB
    unsigned int* xb    = (unsigned int*)(ws + off); off += (size_t)N_NODES * 64;   // 12.8 MB
    int4* rec      = (int4*)(ws + off); off += (size_t)E_TOT * 4 + 256;             // 13.6 MB
    int* posE      = (int*)(ws + off); off += E_TOT + 256;                          //  3.4 MB
    float* as1     = ws + off; off += (size_t)N_NODES * HEADS;
    float* ad1     = ws + off; off += (size_t)N_NODES * HEADS;
    float2* az     = (float2*)(ws + off); off += (size_t)N_NODES * 2;
    float* ad2     = ws + off; off += N_NODES;
    float* p_src   = ws + off; off += IN_DIM * HEADS;
    float* p_dst   = ws + off; off += IN_DIM * HEADS;
    float* v_s     = ws + off; off += C1;
    float* v_d     = ws + off; off += C1;
    float* v_z     = ws + off; off += C1;
    float* cst     = ws + off; off += 2;
    unsigned int* W1b = (unsigned int*)(ws + off); off += 16384;     // 64 KB packed bf16
    int* rowptr    = (int*)(ws + off); off += N_NODES + 1 + 256;     // +pad
    int* bsum      = (int*)(ws + off); off += 256;
    int* boff      = (int*)(ws + off); off += 256;
    int* deg       = (int*)(ws + off); off += N_NODES;
    hipMemsetAsync(deg, 0, N_NODES * sizeof(int), stream);

    // projection collapses + W1 bf16 B-fragment packing
    prep_kernel<<<1, 512, 0, stream>>>(W1, a_src1, a_dst1, W2, a_src2, a_dst2,
                                       b2, fc_w, fc_b, p_src, p_dst, v_s, v_d, v_z, cst, W1b);

    // fused: per-node proj + x->bf16 convert; count claims positions (posE)
    convproj_count_kernel<<<CP_BLOCKS + COUNT_BLOCKS, 256, 0, stream>>>(
        x, p_src, p_dst, dstA, as1, ad1, xb, deg, posE);

    // CSR: parallel scan + atomic-free fill (one 16 B sorted record per edge)
    blocksum_kernel<<<NB_SCAN, 256, 0, stream>>>(deg, bsum);
    scanbsum_kernel<<<1, 256, 0, stream>>>(bsum, boff);
    expand_kernel<<<NB_SCAN, 256, 0, stream>>>(deg, boff, rowptr);
    fillw3_kernel<<<COUNT_BLOCKS, 256, 0, stream>>>(srcA, dstA, rowptr, posE,
                                                    as1, ad1, rec);

    // layer-1 aggregation in bf16 x-space (x8 unroll)
    agg1x_kernel<<<(N_NODES * 64 + 255) / 256, 256, 0, stream>>>(rowptr, rec, xb, xaggb);

    // MFMA MLP (phase C collapsed; epilogue in registers)
    mlp7_kernel<<<N_NODES / 16, 256, 0, stream>>>(xaggb, W1b, b1, v_s, v_d, v_z, az, ad2);

    // layer 2 + final: scalar gather
    agg2z_kernel<<<(N_NODES * 8 + 255) / 256, 256, 0, stream>>>(rowptr, rec, az, ad2, cst, out);
}

// Round 19
// 250.558 us; speedup vs baseline: 1.0213x; 1.0213x over previous
//
#include <hip/hip_runtime.h>
#include <hip/hip_fp16.h>

#define N_NODES 50000
#define N_EDGES 800000
#define E_TOT   850000           // edges + self loops
#define IN_DIM  128
#define HID     64
#define HEADS   4
#define C1      256              // HEADS*HID
#define OUT_DIM 64
#define NEG_SLOPE 0.2f

#define CP_NODES   32                              // nodes per proj block
#define CP_BLOCKS  ((N_NODES + CP_NODES - 1) / CP_NODES)   // 1563
#define COUNT_BLOCKS ((E_TOT + 255) / 256)         // 3321
#define NB_SCAN ((N_NODES + 255) / 256)            // 196

typedef __attribute__((ext_vector_type(8))) short v8s;   // 8 bf16 (4 VGPRs)
typedef __attribute__((ext_vector_type(4))) float v4f;   // MFMA accumulator

// ---- bf16 helpers (manual: bf16 = top 16 bits of fp32, RNE) ----------------
__device__ __forceinline__ unsigned int bf16_rne(float f) {
    unsigned int u = __float_as_uint(f);
    return (u + 0x7FFFu + ((u >> 16) & 1u)) >> 16;
}
__device__ __forceinline__ unsigned int bf16_pack2(float a, float b) {
    return bf16_rne(a) | (bf16_rne(b) << 16);
}
__device__ __forceinline__ float bf16_lo(unsigned int u) { return __uint_as_float(u << 16); }
__device__ __forceinline__ float bf16_hi(unsigned int u) { return __uint_as_float(u & 0xFFFF0000u); }

// ---- fp16 pack helpers for edge weights ------------------------------------
__device__ __forceinline__ unsigned int f16_pack2(float a, float b) {
    __half2 h = __floats2half2_rn(a, b);
    return *(unsigned int*)&h;
}
__device__ __forceinline__ float2 f16_unp2(unsigned int u) {
    __half2 h = *(__half2*)&u;
    return __half22float2(h);
}

// ---------------------------------------------------------------------------
// prep: p_src/p_dst collapse the layer-1 logit projection; v_s/v_d/v_z
// collapse ALL consumers of h2; cst = b2.fc_w + fc_b; W1 -> bf16 B-fragments.
// ---------------------------------------------------------------------------
__global__ __launch_bounds__(512) void prep_kernel(
    const float* __restrict__ W1, const float* __restrict__ a_src1,
    const float* __restrict__ a_dst1,
    const float* __restrict__ W2, const float* __restrict__ a_src2,
    const float* __restrict__ a_dst2, const float* __restrict__ b2,
    const float* __restrict__ fc_w, const float* __restrict__ fc_b,
    float* __restrict__ p_src, float* __restrict__ p_dst,
    float* __restrict__ v_s, float* __restrict__ v_d, float* __restrict__ v_z,
    float* __restrict__ cst, unsigned int* __restrict__ W1b)
{
    const int t = threadIdx.x;                 // 512 = 128 k * 4 h
    const int k = t >> 2, h = t & 3;
    const float* wrow = W1 + k * C1 + h * HID;
    const float* as = a_src1 + h * HID;
    const float* ad = a_dst1 + h * HID;
    float s = 0.f, d = 0.f;
    for (int c = 0; c < HID; c++) {
        float w = wrow[c];
        s = fmaf(w, as[c], s);
        d = fmaf(w, ad[c], d);
    }
    p_src[k * HEADS + h] = s;
    p_dst[k * HEADS + h] = d;

    if (t < C1) {                              // layer-2 collapse vectors
        const float* w2row = W2 + t * OUT_DIM;
        float vs = 0.f, vd = 0.f, vz = 0.f;
        for (int c = 0; c < OUT_DIM; c++) {
            float w = w2row[c];
            vs = fmaf(w, a_src2[c], vs);
            vd = fmaf(w, a_dst2[c], vd);
            vz = fmaf(w, fc_w[c], vz);
        }
        v_s[t] = vs; v_d[t] = vd; v_z[t] = vz;
    }
    if (t == 0) {
        float s2 = 0.f;
        for (int c = 0; c < OUT_DIM; c++) s2 = fmaf(b2[c], fc_w[c], s2);
        cst[0] = s2 + fc_b[0];
    }

    // W1 -> bf16 B-fragment packing (16384 uints = 64 KB)
    for (int idx = t; idx < 16384; idx += 512) {
        int i    = idx & 3;
        int lane = (idx >> 2) & 63;
        int kk   = (idx >> 8) & 3;
        int nt   = (idx >> 10) & 3;
        int hh   = idx >> 12;
        int k0 = kk * 32 + (lane >> 4) * 8 + i * 2;
        int c  = hh * 64 + nt * 16 + (lane & 15);
        W1b[idx] = bf16_pack2(W1[(size_t)k0 * C1 + c], W1[(size_t)(k0 + 1) * C1 + c]);
    }
}

// ---------------------------------------------------------------------------
// convproj_count: fused launch (round-17 proven mapping).
//  Blocks [0, CP_BLOCKS): 32 nodes/block; wave loops 8 contiguous nodes,
//    lane = 2 channels, width-64 shuffle reduce (conflict-free LDS reads).
//  Blocks [CP_BLOCKS, +COUNT_BLOCKS): degree count; stores posE[j].
// ---------------------------------------------------------------------------
__global__ __launch_bounds__(256) void convproj_count_kernel(
    const float* __restrict__ x, const float* __restrict__ p_src,
    const float* __restrict__ p_dst, const int* __restrict__ dst_a,
    float* __restrict__ as1, float* __restrict__ ad1,
    unsigned int* __restrict__ xb, int* __restrict__ deg,
    int* __restrict__ posE)
{
    if (blockIdx.x >= CP_BLOCKS) {             // ---- count part ----
        int j = (blockIdx.x - CP_BLOCKS) * 256 + threadIdx.x;
        if (j < E_TOT) {
            int d = (j < N_EDGES) ? dst_a[j] : (j - N_EDGES);   // self loop
            posE[j] = atomicAdd(&deg[d], 1);
        }
        return;
    }
    // ---- proj + convert part ----
    __shared__ float ps[IN_DIM * HEADS];       // 2 KB
    __shared__ float pd[IN_DIM * HEADS];       // 2 KB
    const int t = threadIdx.x;
    for (int i = t; i < IN_DIM * HEADS; i += 256) { ps[i] = p_src[i]; pd[i] = p_dst[i]; }
    __syncthreads();
    const int wv   = t >> 6;
    const int lane = t & 63;
    float4 p0 = *(const float4*)(ps + (lane * 2) * HEADS);
    float4 p1 = *(const float4*)(ps + (lane * 2 + 1) * HEADS);
    float4 q0 = *(const float4*)(pd + (lane * 2) * HEADS);
    float4 q1 = *(const float4*)(pd + (lane * 2 + 1) * HEADS);
    const int nodeBase = blockIdx.x * CP_NODES + wv * 8;   // wave: 8 contiguous nodes
    #pragma unroll
    for (int i = 0; i < 8; i++) {
        const int node = nodeBase + i;
        if (node >= N_NODES) break;
        float2 xv = *(const float2*)(x + (size_t)node * IN_DIM + lane * 2);
        xb[(size_t)node * 64 + lane] = bf16_pack2(xv.x, xv.y);
        float s0 = xv.x * p0.x + xv.y * p1.x;
        float s1 = xv.x * p0.y + xv.y * p1.y;
        float s2 = xv.x * p0.z + xv.y * p1.z;
        float s3 = xv.x * p0.w + xv.y * p1.w;
        float d0 = xv.x * q0.x + xv.y * q1.x;
        float d1 = xv.x * q0.y + xv.y * q1.y;
        float d2 = xv.x * q0.z + xv.y * q1.z;
        float d3 = xv.x * q0.w + xv.y * q1.w;
        #pragma unroll
        for (int off = 32; off; off >>= 1) {
            s0 += __shfl_down(s0, off, 64); s1 += __shfl_down(s1, off, 64);
            s2 += __shfl_down(s2, off, 64); s3 += __shfl_down(s3, off, 64);
            d0 += __shfl_down(d0, off, 64); d1 += __shfl_down(d1, off, 64);
            d2 += __shfl_down(d2, off, 64); d3 += __shfl_down(d3, off, 64);
        }
        if (lane == 0) {
            float4 sv = {s0, s1, s2, s3};
            float4 dv = {d0, d1, d2, d3};
            *(float4*)(as1 + node * 4) = sv;
            *(float4*)(ad1 + node * 4) = dv;
        }
    }
}

// ---------------------------------------------------------------------------
// Parallel CSR scan: blocksum -> scanbsum -> expand
// ---------------------------------------------------------------------------
__global__ __launch_bounds__(256) void blocksum_kernel(
    const int* __restrict__ deg, int* __restrict__ bsum)
{
    __shared__ int ps[256];
    const int t = threadIdx.x;
    int i = blockIdx.x * 256 + t;
    ps[t] = (i < N_NODES) ? deg[i] : 0;
    __syncthreads();
    for (int off = 128; off; off >>= 1) {
        if (t < off) ps[t] += ps[t + off];
        __syncthreads();
    }
    if (t == 0) bsum[blockIdx.x] = ps[0];
}

__global__ __launch_bounds__(256) void scanbsum_kernel(
    const int* __restrict__ bsum, int* __restrict__ boff)
{
    __shared__ int ps[256];
    const int t = threadIdx.x;
    ps[t] = (t < NB_SCAN) ? bsum[t] : 0;
    __syncthreads();
    for (int off = 1; off < 256; off <<= 1) {
        int u = (t >= off) ? ps[t - off] : 0;
        __syncthreads();
        ps[t] += u;
        __syncthreads();
    }
    boff[t] = (t > 0) ? ps[t - 1] : 0;         // exclusive
}

__global__ __launch_bounds__(256) void expand_kernel(
    const int* __restrict__ deg, const int* __restrict__ boff,
    int* __restrict__ rowptr)
{
    __shared__ int ps[256];
    const int t = threadIdx.x;
    int i = blockIdx.x * 256 + t;
    int v = (i < N_NODES) ? deg[i] : 0;
    ps[t] = v;
    __syncthreads();
    for (int off = 1; off < 256; off <<= 1) {
        int u = (t >= off) ? ps[t - off] : 0;
        __syncthreads();
        ps[t] += u;
        __syncthreads();
    }
    if (i <= N_NODES) rowptr[i] = boff[blockIdx.x] + ps[t] - v;   // exclusive
}

// ---------------------------------------------------------------------------
// fillw3: atomic-free CSR fill with ONE 16 B sorted record per edge:
// rec[slot] = {src, w01(2xf16), w23(2xf16), 0}.
// ---------------------------------------------------------------------------
__global__ void fillw3_kernel(const int* __restrict__ src_a, const int* __restrict__ dst_a,
                              const int* __restrict__ rowptr, const int* __restrict__ posE,
                              const float* __restrict__ as1, const float* __restrict__ ad1,
                              int4* __restrict__ rec)
{
    int j = blockIdx.x * blockDim.x + threadIdx.x;
    if (j >= E_TOT) return;
    int s, d;
    if (j < N_EDGES) { s = src_a[j]; d = dst_a[j]; }
    else             { s = j - N_EDGES; d = s; }
    int slot = rowptr[d] + posE[j];
    float4 A  = *(const float4*)(as1 + s * 4);
    float4 Dv = *(const float4*)(ad1 + d * 4);
    float a0 = A.x + Dv.x, a1 = A.y + Dv.y, a2 = A.z + Dv.z, a3 = A.w + Dv.w;
    a0 = a0 > 0.f ? a0 : NEG_SLOPE * a0;
    a1 = a1 > 0.f ? a1 : NEG_SLOPE * a1;
    a2 = a2 > 0.f ? a2 : NEG_SLOPE * a2;
    a3 = a3 > 0.f ? a3 : NEG_SLOPE * a3;
    int4 r;
    r.x = s;
    r.y = (int)f16_pack2(__expf(a0), __expf(a1));
    r.z = (int)f16_pack2(__expf(a2), __expf(a3));
    r.w = 0;
    rec[slot] = r;                             // single 16 B scatter
}

// ---------------------------------------------------------------------------
// agg1x: xaggb[n][h][k] (bf16) = softmax-weighted sum of xb[src] rows (bf16).
// One wave per dst node; per-edge {src, weights} in one sorted record;
// unroll x4 (round-17 proven sweet spot: VGPR 32, high occupancy).
// ---------------------------------------------------------------------------
__global__ __launch_bounds__(256) void agg1x_kernel(
    const int* __restrict__ rowptr, const int4* __restrict__ rec,
    const unsigned int* __restrict__ xb, unsigned int* __restrict__ xaggb)
{
    int gid  = blockIdx.x * blockDim.x + threadIdx.x;
    int n    = gid >> 6;
    int lane = threadIdx.x & 63;
    if (n >= N_NODES) return;
    const int e0 = rowptr[n], e1 = rowptr[n + 1];

    float2 acc0 = {0,0}, acc1 = {0,0}, acc2 = {0,0}, acc3 = {0,0};
    float den0 = 0, den1 = 0, den2 = 0, den3 = 0;
    int e = e0;
    for (; e + 4 <= e1; e += 4) {              // 4 gathers in flight
        int4 r0 = rec[e],     r1 = rec[e + 1];
        int4 r2 = rec[e + 2], r3 = rec[e + 3];
        unsigned int xu0 = xb[(size_t)r0.x * 64 + lane];
        unsigned int xu1 = xb[(size_t)r1.x * 64 + lane];
        unsigned int xu2 = xb[(size_t)r2.x * 64 + lane];
        unsigned int xu3 = xb[(size_t)r3.x * 64 + lane];
        float2 W0a = f16_unp2(r0.y), W0b = f16_unp2(r0.z);
        float2 W1a = f16_unp2(r1.y), W1b_ = f16_unp2(r1.z);
        float2 W2a = f16_unp2(r2.y), W2b = f16_unp2(r2.z);
        float2 W3a = f16_unp2(r3.y), W3b = f16_unp2(r3.z);
        float a0 = bf16_lo(xu0), b0 = bf16_hi(xu0);
        float a1 = bf16_lo(xu1), b1 = bf16_hi(xu1);
        float a2 = bf16_lo(xu2), b2 = bf16_hi(xu2);
        float a3 = bf16_lo(xu3), b3 = bf16_hi(xu3);
        acc0.x = fmaf(W0a.x, a0, acc0.x); acc0.y = fmaf(W0a.x, b0, acc0.y);
        acc1.x = fmaf(W0a.y, a0, acc1.x); acc1.y = fmaf(W0a.y, b0, acc1.y);
        acc2.x = fmaf(W0b.x, a0, acc2.x); acc2.y = fmaf(W0b.x, b0, acc2.y);
        acc3.x = fmaf(W0b.y, a0, acc3.x); acc3.y = fmaf(W0b.y, b0, acc3.y);
        acc0.x = fmaf(W1a.x, a1, acc0.x); acc0.y = fmaf(W1a.x, b1, acc0.y);
        acc1.x = fmaf(W1a.y, a1, acc1.x); acc1.y = fmaf(W1a.y, b1, acc1.y);
        acc2.x = fmaf(W1b_.x, a1, acc2.x); acc2.y = fmaf(W1b_.x, b1, acc2.y);
        acc3.x = fmaf(W1b_.y, a1, acc3.x); acc3.y = fmaf(W1b_.y, b1, acc3.y);
        acc0.x = fmaf(W2a.x, a2, acc0.x); acc0.y = fmaf(W2a.x, b2, acc0.y);
        acc1.x = fmaf(W2a.y, a2, acc1.x); acc1.y = fmaf(W2a.y, b2, acc1.y);
        acc2.x = fmaf(W2b.x, a2, acc2.x); acc2.y = fmaf(W2b.x, b2, acc2.y);
        acc3.x = fmaf(W2b.y, a2, acc3.x); acc3.y = fmaf(W2b.y, b2, acc3.y);
        acc0.x = fmaf(W3a.x, a3, acc0.x); acc0.y = fmaf(W3a.x, b3, acc0.y);
        acc1.x = fmaf(W3a.y, a3, acc1.x); acc1.y = fmaf(W3a.y, b3, acc1.y);
        acc2.x = fmaf(W3b.x, a3, acc2.x); acc2.y = fmaf(W3b.x, b3, acc2.y);
        acc3.x = fmaf(W3b.y, a3, acc3.x); acc3.y = fmaf(W3b.y, b3, acc3.y);
        den0 += (W0a.x + W1a.x) + (W2a.x + W3a.x);
        den1 += (W0a.y + W1a.y) + (W2a.y + W3a.y);
        den2 += (W0b.x + W1b_.x) + (W2b.x + W3b.x);
        den3 += (W0b.y + W1b_.y) + (W2b.y + W3b.y);
    }
    for (; e < e1; e++) {
        int4 r0 = rec[e];
        unsigned int xu = xb[(size_t)r0.x * 64 + lane];
        float2 Wa = f16_unp2(r0.y), Wb = f16_unp2(r0.z);
        float xa = bf16_lo(xu), xbv = bf16_hi(xu);
        acc0.x = fmaf(Wa.x, xa, acc0.x); acc0.y = fmaf(Wa.x, xbv, acc0.y);
        acc1.x = fmaf(Wa.y, xa, acc1.x); acc1.y = fmaf(Wa.y, xbv, acc1.y);
        acc2.x = fmaf(Wb.x, xa, acc2.x); acc2.y = fmaf(Wb.x, xbv, acc2.y);
        acc3.x = fmaf(Wb.y, xa, acc3.x); acc3.y = fmaf(Wb.y, xbv, acc3.y);
        den0 += Wa.x; den1 += Wa.y; den2 += Wb.x; den3 += Wb.y;
    }
    float i0 = 1.f / (den0 + 1e-16f), i1 = 1.f / (den1 + 1e-16f);
    float i2 = 1.f / (den2 + 1e-16f), i3 = 1.f / (den3 + 1e-16f);
    unsigned int* o = xaggb + (size_t)n * 256 + lane;      // row = 256 uints
    o[0 * 64] = bf16_pack2(acc0.x * i0, acc0.y * i0);
    o[1 * 64] = bf16_pack2(acc1.x * i1, acc1.y * i1);
    o[2 * 64] = bf16_pack2(acc2.x * i2, acc2.y * i2);
    o[3 * 64] = bf16_pack2(acc3.x * i3, acc3.y * i3);
}

// ---------------------------------------------------------------------------
// mlp7: MFMA phase B. 16 nodes/block, wave = head. (unchanged)
// ---------------------------------------------------------------------------
__global__ __launch_bounds__(256, 4) void mlp7_kernel(
    const unsigned int* __restrict__ xaggb,
    const unsigned int* __restrict__ W1b, const float* __restrict__ b1,
    const float* __restrict__ v_s, const float* __restrict__ v_d,
    const float* __restrict__ v_z,
    float2* __restrict__ az, float* __restrict__ ad2)
{
    __shared__ unsigned int xsh[16 * 260];     // 16.6 KB bf16 tile (+pad)
    __shared__ float pr[4 * 16 * 3];           // 768 B cross-wave partials
    const int t = threadIdx.x;
    const int nodeBase = blockIdx.x * 16;
    const int h = t >> 6;                      // wave = head
    const int lane = t & 63;

    {   // ---- Phase A: stage 16x512ch bf16 tile (no conversion) ----
        const unsigned int* gsrc = xaggb + (size_t)nodeBase * 256;
        #pragma unroll
        for (int i = 0; i < 4; i++) {
            int iu = i * 1024 + t * 4;         // uint index in 4096-uint tile
            uint4 v = *(const uint4*)(gsrc + iu);
            int n = iu >> 8, c = iu & 255;
            *(uint4*)(xsh + n * 260 + c) = v;
        }
    }
    __syncthreads();

    {   // ---- Phase B: MFMA + register epilogue ----
        const int m = lane & 15, quad = lane >> 4;
        const unsigned int* abase = xsh + m * 260 + h * 64 + quad * 4;
        v8s af0 = *(const v8s*)(abase + 0);
        v8s af1 = *(const v8s*)(abase + 16);
        v8s af2 = *(const v8s*)(abase + 32);
        v8s af3 = *(const v8s*)(abase + 48);

        float Sr[4] = {0,0,0,0}, Dr[4] = {0,0,0,0}, Zr[4] = {0,0,0,0};
        #pragma unroll
        for (int nt = 0; nt < 4; nt++) {
            const unsigned int* bbase = W1b + (size_t)(h * 16 + nt * 4) * 256 + lane * 4;
            v4f acc = {0.f, 0.f, 0.f, 0.f};
            acc = __builtin_amdgcn_mfma_f32_16x16x32_bf16(af0, *(const v8s*)(bbase + 0 * 256), acc, 0, 0, 0);
            acc = __builtin_amdgcn_mfma_f32_16x16x32_bf16(af1, *(const v8s*)(bbase + 1 * 256), acc, 0, 0, 0);
            acc = __builtin_amdgcn_mfma_f32_16x16x32_bf16(af2, *(const v8s*)(bbase + 2 * 256), acc, 0, 0, 0);
            acc = __builtin_amdgcn_mfma_f32_16x16x32_bf16(af3, *(const v8s*)(bbase + 3 * 256), acc, 0, 0, 0);
            const int c = h * 64 + nt * 16 + m;
            float bb = b1[c], vsc = v_s[c], vdc = v_d[c], vzc = v_z[c];
            #pragma unroll
            for (int r = 0; r < 4; r++) {
                float o = acc[r] + bb;
                o = o > 0.f ? o : __expf(o) - 1.f;     // ELU
                Sr[r] = fmaf(o, vsc, Sr[r]);
                Dr[r] = fmaf(o, vdc, Dr[r]);
                Zr[r] = fmaf(o, vzc, Zr[r]);
            }
        }
        #pragma unroll
        for (int off = 8; off; off >>= 1) {            // reduce over 16 cols
            #pragma unroll
            for (int r = 0; r < 4; r++) {
                Sr[r] += __shfl_down(Sr[r], off, 16);
                Dr[r] += __shfl_down(Dr[r], off, 16);
                Zr[r] += __shfl_down(Zr[r], off, 16);
            }
        }
        if (m == 0) {
            #pragma unroll
            for (int r = 0; r < 4; r++) {
                const int row = quad * 4 + r;          // local node 0..15
                pr[(h * 16 + row) * 3 + 0] = Sr[r];
                pr[(h * 16 + row) * 3 + 1] = Dr[r];
                pr[(h * 16 + row) * 3 + 2] = Zr[r];
            }
        }
    }
    __syncthreads();

    if (t < 16) {   // ---- cross-head reduce + store ----
        float s = 0.f, d = 0.f, z = 0.f;
        #pragma unroll
        for (int w = 0; w < 4; w++) {
            s += pr[(w * 16 + t) * 3 + 0];
            d += pr[(w * 16 + t) * 3 + 1];
            z += pr[(w * 16 + t) * 3 + 2];
        }
        const int node = nodeBase + t;
        float2 azv = {s, z};
        az[node]  = azv;
        ad2[node] = d;
    }
}

// ---------------------------------------------------------------------------
// agg2z: out[n] = sum_e w_e * z[src] / sum_e w_e + cst.  Reads rec[e].x.
// ---------------------------------------------------------------------------
__global__ __launch_bounds__(256) void agg2z_kernel(
    const int* __restrict__ rowptr, const int4* __restrict__ rec,
    const float2* __restrict__ az, const float* __restrict__ ad2,
    const float* __restrict__ cst, float* __restrict__ out)
{
    int gid  = blockIdx.x * blockDim.x + threadIdx.x;
    int n    = gid >> 3;                       // 8 lanes per node
    int sl   = threadIdx.x & 7;
    if (n >= N_NODES) return;
    const float adh = ad2[n];
    const int e0 = rowptr[n], e1 = rowptr[n + 1];

    float acc = 0.f, den = 0.f;
    for (int e = e0 + sl; e < e1; e += 8) {
        int s = rec[e].x;
        float2 v = az[s];
        float a = v.x + adh;
        a = a > 0.f ? a : NEG_SLOPE * a;
        float w = __expf(a);
        acc = fmaf(w, v.y, acc);
        den += w;
    }
    #pragma unroll
    for (int off = 4; off; off >>= 1) {
        acc += __shfl_down(acc, off, 8);
        den += __shfl_down(den, off, 8);
    }
    if (sl == 0) out[n] = acc / (den + 1e-16f) + cst[0];
}

extern "C" void kernel_launch(void* const* d_in, const int* in_sizes, int n_in,
                              void* d_out, int out_size, void* d_ws, size_t ws_size,
                              hipStream_t stream)
{
    const float* x      = (const float*)d_in[0];
    const int*   ei     = (const int*)d_in[1];
    const float* W1     = (const float*)d_in[2];
    const float* a_src1 = (const float*)d_in[3];
    const float* a_dst1 = (const float*)d_in[4];
    const float* b1     = (const float*)d_in[5];
    const float* W2     = (const float*)d_in[6];
    const float* a_src2 = (const float*)d_in[7];
    const float* a_dst2 = (const float*)d_in[8];
    const float* b2     = (const float*)d_in[9];
    const float* fc_w   = (const float*)d_in[10];
    const float* fc_b   = (const float*)d_in[11];
    float* out = (float*)d_out;

    const int* srcA = ei;
    const int* dstA = ei + N_EDGES;

    // workspace layout (pads after index buffers as OOB insurance)
    float* ws = (float*)d_ws;
    size_t off = 0;
    unsigned int* xaggb = (unsigned int*)(ws + off); off += (size_t)N_NODES * 256;  // 51.2 MB
    unsigned int* xb    = (unsigned int*)(ws + off); off += (size_t)N_NODES * 64;   // 12.8 MB
    int4* rec      = (int4*)(ws + off); off += (size_t)E_TOT * 4 + 256;             // 13.6 MB
    int* posE      = (int*)(ws + off); off += E_TOT + 256;                          //  3.4 MB
    float* as1     = ws + off; off += (size_t)N_NODES * HEADS;
    float* ad1     = ws + off; off += (size_t)N_NODES * HEADS;
    float2* az     = (float2*)(ws + off); off += (size_t)N_NODES * 2;
    float* ad2     = ws + off; off += N_NODES;
    float* p_src   = ws + off; off += IN_DIM * HEADS;
    float* p_dst   = ws + off; off += IN_DIM * HEADS;
    float* v_s     = ws + off; off += C1;
    float* v_d     = ws + off; off += C1;
    float* v_z     = ws + off; off += C1;
    float* cst     = ws + off; off += 2;
    unsigned int* W1b = (unsigned int*)(ws + off); off += 16384;     // 64 KB packed bf16
    int* rowptr    = (int*)(ws + off); off += N_NODES + 1 + 256;     // +pad
    int* bsum      = (int*)(ws + off); off += 256;
    int* boff      = (int*)(ws + off); off += 256;
    int* deg       = (int*)(ws + off); off += N_NODES;
    hipMemsetAsync(deg, 0, N_NODES * sizeof(int), stream);

    // projection collapses + W1 bf16 B-fragment packing
    prep_kernel<<<1, 512, 0, stream>>>(W1, a_src1, a_dst1, W2, a_src2, a_dst2,
                                       b2, fc_w, fc_b, p_src, p_dst, v_s, v_d, v_z, cst, W1b);

    // fused: per-node proj + x->bf16 convert; count claims positions (posE)
    convproj_count_kernel<<<CP_BLOCKS + COUNT_BLOCKS, 256, 0, stream>>>(
        x, p_src, p_dst, dstA, as1, ad1, xb, deg, posE);

    // CSR: parallel scan + atomic-free fill (one 16 B sorted record per edge)
    blocksum_kernel<<<NB_SCAN, 256, 0, stream>>>(deg, bsum);
    scanbsum_kernel<<<1, 256, 0, stream>>>(bsum, boff);
    expand_kernel<<<NB_SCAN, 256, 0, stream>>>(deg, boff, rowptr);
    fillw3_kernel<<<COUNT_BLOCKS, 256, 0, stream>>>(srcA, dstA, rowptr, posE,
                                                    as1, ad1, rec);

    // layer-1 aggregation in bf16 x-space (x4 unroll — proven sweet spot)
    agg1x_kernel<<<(N_NODES * 64 + 255) / 256, 256, 0, stream>>>(rowptr, rec, xb, xaggb);

    // MFMA MLP (phase C collapsed; epilogue in registers)
    mlp7_kernel<<<N_NODES / 16, 256, 0, stream>>>(xaggb, W1b, b1, v_s, v_d, v_z, az, ad2);

    // layer 2 + final: scalar gather
    agg2z_kernel<<<(N_NODES * 8 + 255) / 256, 256, 0, stream>>>(rowptr, rec, az, ad2, cst, out);
}